// Round 9
// baseline (1103.101 us; speedup 1.0000x reference)
//
#include <hip/hip_runtime.h>
#include <stdint.h>

// TrajEncoder: embedding gather + LSTM(D=128,H=256) over T=512, output h at valid_len-1.
// R9 = R8 + __attribute__((amdgpu_waves_per_eu(2,2))): pin allocator to exactly 2
// waves/EU -> 256-VGPR budget. R6/R7/R8 proved launch_bounds' 2nd arg does NOT steer
// the allocator (cap stayed at 65536/maxThreads = half-file = 2 blocks/CU), so the
// 192-u32 weight arrays spilled: R8's WRITE_SIZE 49MB == one-time spill-out (192 u32 x
// 512thr x 128WG x 4B), then per-step L2 re-reads -> L2-BW-bound, VALUBusy 9.6%.
// Architecture unchanged: 2 WGs (512 thr) per batch, runtime same-XCD pairing
// (HW_REG_XCC_ID + per-XCD rank, handshake-hardened with orphan rescue), h-exchange via
// sc0 (L1-bypass, L2-coherent) with bounded poll + permanent agent-scope fallback.
// Epoch encoding: h in (-1,1) => bit14 clear; ~pk sets it; 0xFF init rejects phase-0.

#define BB 64
#define TT 512
#define DD 128
#define HH 256

// ws layout (u32 units)
#define WS_BCNT   0        // global batch counter
#define WS_OCNT   1        // global orphan counter
#define WS_RANK   8        // [8..16) per-XCD rank counters
#define WS_HELLO  64       // [64..576)   per-XCD pair hello (8 x 64)
#define WS_BTAB   576      // [576..1088) per-XCD pair->batch+1 / -1=abandoned (8 x 64)
#define WS_OHELLO 1600     // [1600..1664) orphan hello
#define WS_OBTAB  1664     // [1664..1728) orphan pair->batch+1
#define WS_EXC    2048     // sc0 exchange [2][BB][128]; then agent region same size

typedef __fp16 half2v __attribute__((ext_vector_type(2)));

__device__ __forceinline__ uint32_t pk_f16(float lo, float hi) {
    half2v h = __builtin_amdgcn_cvt_pkrtz(lo, hi);
    return __builtin_bit_cast(uint32_t, h);
}

__device__ __forceinline__ float dot2(uint32_t a, uint32_t b, float acc) {
    return __builtin_amdgcn_fdot2(__builtin_bit_cast(half2v, a),
                                  __builtin_bit_cast(half2v, b), acc, false);
}

template<int CTRL>
__device__ __forceinline__ float dpp_add(float a) {
    int m = __builtin_amdgcn_update_dpp(0, __builtin_bit_cast(int, a), CTRL, 0xF, 0xF, false);
    return a + __builtin_bit_cast(float, m);
}

__device__ __forceinline__ uint32_t load_sc0(const uint32_t* p) {
    uint32_t v;
    asm volatile("global_load_dword %0, %1, off sc0\n\ts_waitcnt vmcnt(0)"
                 : "=v"(v) : "v"(p) : "memory");
    return v;
}
__device__ __forceinline__ void store_sc0(uint32_t* p, uint32_t v) {
    asm volatile("global_store_dword %0, %1, off sc0" :: "v"(p), "v"(v) : "memory");
}

__device__ __forceinline__ int a_ld(int* p) {
    return __hip_atomic_load(p, __ATOMIC_RELAXED, __HIP_MEMORY_SCOPE_AGENT);
}
__device__ __forceinline__ void a_st(int* p, int v) {
    __hip_atomic_store(p, v, __ATOMIC_RELAXED, __HIP_MEMORY_SCOPE_AGENT);
}
__device__ __forceinline__ int a_add(int* p) {
    return __hip_atomic_fetch_add(p, 1, __ATOMIC_RELAXED, __HIP_MEMORY_SCOPE_AGENT);
}

__device__ __forceinline__ float fsig(float x)  { return 1.f / (1.f + __expf(-x)); }
__device__ __forceinline__ float ftanh(float x) { return 1.f - 2.f / (__expf(2.f * x) + 1.f); }

__global__ __launch_bounds__(512, 1) __attribute__((amdgpu_waves_per_eu(2, 2)))
void lstm_pair_kernel(const int* __restrict__ path, const int* __restrict__ vlen,
                      const float* __restrict__ emb, const float* __restrict__ Wih,
                      const float* __restrict__ Whh, const float* __restrict__ bih,
                      const float* __restrict__ bhh, float* __restrict__ out,
                      uint32_t* ctl) {
    uint32_t* excF = ctl + WS_EXC;              // sc0 region
    uint32_t* excA = excF + 2 * BB * 128;       // agent fallback region
    const int tid = threadIdx.x;

    // ---- handshake-hardened same-XCD pairing ----
    __shared__ int s_bh;
    if (tid == 0) {
        uint32_t xcc;
        asm volatile("s_getreg_b32 %0, hwreg(20, 0, 4)" : "=s"(xcc));  // HW_REG_XCC_ID
        xcc &= 7;
        int rank  = a_add((int*)&ctl[WS_RANK + xcc]);
        int p     = rank >> 1;
        int half  = rank & 1;
        int batch = BB;
        bool orphan = false;
        if (p < 64) {
            int* hel = (int*)&ctl[WS_HELLO + xcc * 64 + p];
            int* bt  = (int*)&ctl[WS_BTAB  + xcc * 64 + p];
            if (half) {
                a_st(hel, 1);                               // commit to this pair
                int v = 0, w = 1 << 18;
                do { v = a_ld(bt); if (!v) __builtin_amdgcn_s_sleep(2); } while (!v && --w);
                if (v > 0) batch = v - 1;
                else if (v < 0) orphan = true;              // partner gave up on us
            } else {
                int v = 0;
                for (int it = 0; it < 300 && !v; ++it) {    // ~60us: partner hello
                    v = a_ld(hel);
                    if (!v) __builtin_amdgcn_s_sleep(8);
                }
                if (v) { batch = a_add((int*)&ctl[WS_BCNT]); a_st(bt, batch + 1); }
                else   { a_st(bt, -1); orphan = true; }     // no partner on this XCD
            }
        } else orphan = true;
        if (orphan) {                                       // global rescue (count is even)
            int o  = a_add((int*)&ctl[WS_OCNT]);
            int op = o >> 1;
            half   = o & 1;
            batch  = BB;
            if (op < 32) {
                int* ohel = (int*)&ctl[WS_OHELLO + op];
                int* obt  = (int*)&ctl[WS_OBTAB  + op];
                if (half) {
                    a_st(ohel, 1);
                    int v = 0, w = 1 << 18;
                    do { v = a_ld(obt); if (!v) __builtin_amdgcn_s_sleep(2); } while (!v && --w);
                    if (v > 0) batch = v - 1;
                } else {
                    int v = 0, w = 1 << 18;
                    do { v = a_ld(ohel); if (!v) __builtin_amdgcn_s_sleep(2); } while (!v && --w);
                    if (v) { batch = a_add((int*)&ctl[WS_BCNT]); a_st(obt, batch + 1); }
                }
            }
        }
        s_bh = (batch << 1) | half;
    }
    __syncthreads();
    const int b    = s_bh >> 1;
    const int half = s_bh & 1;          // owns h units [128*half, 128*half+128)
    if (b >= BB) return;                // surplus WG

    const int cg = tid & 7;             // col-group: h cols [32cg,+32), x cols [16cg,+16)
    const int rb = tid >> 3;            // row-block 0..63: local gate rows [8rb, 8rb+8)

    __shared__ uint32_t h_pk[8][24];    // full packed h (128 u32 used + pad)
    __shared__ uint32_t x_pk[2][8][12]; // packed x_t, double buffered (64 u32 used + pad)
    __shared__ float    G[512];         // our 512 gate pre-activations
    __shared__ int      path_l[TT];

    // ---- weight slices -> registers: 8 local rows x (16 h-u32 + 8 x-u32) ----
    uint32_t whh[128], wih[64];
#pragma unroll
    for (int rr = 0; rr < 8; ++rr) {
        const int lr   = (rb << 3) + rr;                              // local row 0..511
        const int grow = ((lr >> 7) << 8) + (half << 7) + (lr & 127); // global gate row
        const float* wr = Whh + grow * HH + (cg << 5);
#pragma unroll
        for (int c = 0; c < 16; ++c) whh[rr * 16 + c] = pk_f16(wr[2 * c], wr[2 * c + 1]);
        const float* wr2 = Wih + grow * DD + (cg << 4);
#pragma unroll
        for (int c = 0; c < 8; ++c) wih[rr * 8 + c] = pk_f16(wr2[2 * c], wr2[2 * c + 1]);
    }
    const int L = vlen[b];

    float bi = 0.f, bf = 0.f, bg = 0.f, bo = 0.f;
    if (tid < 128) {
        int u = (half << 7) + tid;
        bi = bih[u]       + bhh[u];
        bf = bih[256 + u] + bhh[256 + u];
        bg = bih[512 + u] + bhh[512 + u];
        bo = bih[768 + u] + bhh[768 + u];
    }
    path_l[tid] = path[b * TT + tid];               // 512 threads == TT
    if (tid < 192) ((uint32_t*)h_pk)[tid] = 0u;     // h_0 = 0 (pads included)
    __syncthreads();

    // x pipeline (waves 6-7): stage x_0, prefetch x_1
    float xr_next = 0.f;
    if (tid >= 384) {
        int e = tid - 384;
        float x0  = emb[(size_t)path_l[0] * DD + e];
        float x0h = __shfl_xor(x0, 1);
        if (!(e & 1)) { int j = e >> 1; x_pk[0][j >> 3][j & 7] = pk_f16(x0, x0h); }
        xr_next = emb[(size_t)path_l[L > 1 ? 1 : 0] * DD + e];
    }
    float c_state = 0.f;
    bool  fast_ok = true;
    __syncthreads();

    for (int t = 0; t < L; ++t) {
        const int slot  = t & 1;
        const int phase = (t >> 1) & 1;
        const uint32_t want = phase ? 0x40004000u : 0u;

        // ---- dots: 8 rows x (32 h + 16 x cols); LDS = 6 x ds_read_b128/thread ----
        const uint4 hv0 = *(const uint4*)&h_pk[cg][0];
        const uint4 hv1 = *(const uint4*)&h_pk[cg][4];
        const uint4 hv2 = *(const uint4*)&h_pk[cg][8];
        const uint4 hv3 = *(const uint4*)&h_pk[cg][12];
        const uint4 xv0 = *(const uint4*)&x_pk[slot][cg][0];
        const uint4 xv1 = *(const uint4*)&x_pk[slot][cg][4];
        float acc[8];
#pragma unroll
        for (int rr = 0; rr < 8; ++rr) {
            float a = 0.f;
            a = dot2(whh[rr * 16 +  0], hv0.x, a);
            a = dot2(whh[rr * 16 +  1], hv0.y, a);
            a = dot2(whh[rr * 16 +  2], hv0.z, a);
            a = dot2(whh[rr * 16 +  3], hv0.w, a);
            a = dot2(whh[rr * 16 +  4], hv1.x, a);
            a = dot2(whh[rr * 16 +  5], hv1.y, a);
            a = dot2(whh[rr * 16 +  6], hv1.z, a);
            a = dot2(whh[rr * 16 +  7], hv1.w, a);
            a = dot2(whh[rr * 16 +  8], hv2.x, a);
            a = dot2(whh[rr * 16 +  9], hv2.y, a);
            a = dot2(whh[rr * 16 + 10], hv2.z, a);
            a = dot2(whh[rr * 16 + 11], hv2.w, a);
            a = dot2(whh[rr * 16 + 12], hv3.x, a);
            a = dot2(whh[rr * 16 + 13], hv3.y, a);
            a = dot2(whh[rr * 16 + 14], hv3.z, a);
            a = dot2(whh[rr * 16 + 15], hv3.w, a);
            a = dot2(wih[rr * 8 + 0], xv0.x, a);
            a = dot2(wih[rr * 8 + 1], xv0.y, a);
            a = dot2(wih[rr * 8 + 2], xv0.z, a);
            a = dot2(wih[rr * 8 + 3], xv0.w, a);
            a = dot2(wih[rr * 8 + 4], xv1.x, a);
            a = dot2(wih[rr * 8 + 5], xv1.y, a);
            a = dot2(wih[rr * 8 + 6], xv1.z, a);
            a = dot2(wih[rr * 8 + 7], xv1.w, a);
            a = dpp_add<0xB1>(a);
            a = dpp_add<0x4E>(a);
            a = dpp_add<0x141>(a);
            acc[rr] = a;
        }
        if (cg == 0) {
            *(float4*)&G[(rb << 3) + 0] = make_float4(acc[0], acc[1], acc[2], acc[3]);
            *(float4*)&G[(rb << 3) + 4] = make_float4(acc[4], acc[5], acc[6], acc[7]);
        }
        __syncthreads();

        // ---- roles: waves0-1 pointwise+publish | wave5 poll | waves6-7 x staging ----
        if (tid < 128) {
            float gi = fsig(G[tid] + bi);
            float gf = fsig(G[128 + tid] + bf);
            float gg = ftanh(G[256 + tid] + bg);
            float go = fsig(G[384 + tid] + bo);
            c_state  = gf * c_state + gi * gg;
            float h  = go * ftanh(c_state);
            if (t == L - 1) out[b * HH + (half << 7) + tid] = h;
            float h1 = __shfl_xor(h, 1);
            if (!(tid & 1)) {
                uint32_t pk = pk_f16(h, h1);
                int j = (half << 6) + (tid >> 1);            // global u32 idx 0..127
                h_pk[j >> 4][j & 15] = pk;                   // own slice via LDS
                uint32_t enc = phase ? ~pk : pk;
                int idx = (slot * BB + b) * 128 + j;
                store_sc0(excF + idx, enc);                  // same-XCD L2 path
                __hip_atomic_store(excA + idx, enc,
                                   __ATOMIC_RELAXED, __HIP_MEMORY_SCOPE_AGENT);
            }
        } else if (tid >= 320 && tid < 384) {
            if (t < L - 1) {
                int c = tid - 320;                           // 64 peer u32s
                int j = ((1 - half) << 6) + c;
                const int idx = (slot * BB + b) * 128 + j;
                uint32_t v; bool got = false;
                if (fast_ok) {
                    int bound = (t == 0) ? 1500 : 400;
                    do {
                        v = load_sc0(excF + idx);
                        got = ((v & 0x40004000u) == want);
                    } while (!got && --bound);
                    if (!got) fast_ok = false;               // permanent fallback
                }
                if (!got) {
                    int spins = 0;
                    do {
                        v = __hip_atomic_load(excA + idx, __ATOMIC_RELAXED,
                                              __HIP_MEMORY_SCOPE_AGENT);
                    } while ((v & 0x40004000u) != want && ++spins < (1 << 20));
                }
                uint32_t d = phase ? ~v : v;
                h_pk[j >> 4][j & 15] = d;
            }
        } else if (tid >= 384) {
            int e = tid - 384;
            float xh = __shfl_xor(xr_next, 1);
            if (!(e & 1)) { int j = e >> 1; x_pk[slot ^ 1][j >> 3][j & 7] = pk_f16(xr_next, xh); }
            int tpf = (t + 2 < TT) ? t + 2 : TT - 1;
            xr_next = emb[(size_t)path_l[tpf] * DD + e];     // prefetch x_{t+2}
        }
        __syncthreads();
    }
}

extern "C" void kernel_launch(void* const* d_in, const int* in_sizes, int n_in,
                              void* d_out, int out_size, void* d_ws, size_t ws_size,
                              hipStream_t stream) {
    const int*   path = (const int*)d_in[0];
    const int*   vlen = (const int*)d_in[1];
    const float* emb  = (const float*)d_in[2];
    const float* Wih  = (const float*)d_in[3];
    const float* Whh  = (const float*)d_in[4];
    const float* bih  = (const float*)d_in[5];
    const float* bhh  = (const float*)d_in[6];

    // control region zeroed; exchange regions 0xFF (bit14 set -> phase-0 reject)
    (void)hipMemsetAsync(d_ws, 0x00, (size_t)WS_EXC * 4, stream);
    (void)hipMemsetAsync((char*)d_ws + (size_t)WS_EXC * 4, 0xFF,
                         (size_t)2 * 2 * BB * 128 * 4, stream);
    lstm_pair_kernel<<<256, 512, 0, stream>>>(path, vlen, emb, Wih, Whh, bih, bhh,
                                              (float*)d_out, (uint32_t*)d_ws);
}

// Round 10
// 890.412 us; speedup vs baseline: 1.2389x; 1.2389x over previous
//
#include <hip/hip_runtime.h>
#include <stdint.h>

// TrajEncoder: embedding gather + LSTM(D=128,H=256) over T=512, output h at valid_len-1.
// R10: 8 WGs (512 thr) per batch, STATIC mapping (blockIdx = b*8+k), grid 512 = 2 WGs/CU.
// Per-WG weight slice is small enough (48 u32/thread, named uint4 vars) to fit the
// MEASURED 128-VGPR budget -- R2..R9 all spilled weights to scratch (VGPR 56/64/128 +
// WRITE_SIZE == array size) and were L2-scratch-BW-bound, not exchange-bound.
// h-exchange: agent-scope atomics, epoch-encoded values (phase0: bit14 of each f16 half
// clear; phase1: ~pk sets bit14), double-buffered slots; 0xFF init rejects phase-0.
// 8-lane DPP reduce: quad xor1, quad xor2, row_half_mirror (R6-proven).

#define BB 64
#define TT 512
#define DD 128
#define HH 256

typedef __fp16 half2v __attribute__((ext_vector_type(2)));

static __device__ __forceinline__ uint32_t pk_f16(float lo, float hi) {
    half2v h = __builtin_amdgcn_cvt_pkrtz(lo, hi);
    return __builtin_bit_cast(uint32_t, h);
}
static __device__ __forceinline__ uint4 pk4(const float* p) {
    return make_uint4(pk_f16(p[0], p[1]), pk_f16(p[2], p[3]),
                      pk_f16(p[4], p[5]), pk_f16(p[6], p[7]));
}
static __device__ __forceinline__ float dot2(uint32_t a, uint32_t b, float acc) {
    return __builtin_amdgcn_fdot2(__builtin_bit_cast(half2v, a),
                                  __builtin_bit_cast(half2v, b), acc, false);
}
static __device__ __forceinline__ float dot8(uint4 w, uint4 v, float a) {
    a = dot2(w.x, v.x, a); a = dot2(w.y, v.y, a);
    a = dot2(w.z, v.z, a); a = dot2(w.w, v.w, a);
    return a;
}

// a += a[perm(lane)] via DPP. 0xB1=quad xor1, 0x4E=quad xor2, 0x141=row_half_mirror
// (p <-> 7-p within each 8-lane half-row; symmetric => rotate-direction-proof).
template<int CTRL>
static __device__ __forceinline__ float dpp_add(float a) {
    int m = __builtin_amdgcn_update_dpp(0, __builtin_bit_cast(int, a), CTRL, 0xF, 0xF, false);
    return a + __builtin_bit_cast(float, m);
}

static __device__ __forceinline__ float fsig(float x)  { return 1.f / (1.f + __expf(-x)); }
static __device__ __forceinline__ float ftanh(float x) { return 1.f - 2.f / (__expf(2.f * x) + 1.f); }

__global__ __launch_bounds__(512)
void lstm_oct_kernel(const int* __restrict__ path, const int* __restrict__ vlen,
                     const float* __restrict__ emb, const float* __restrict__ Wih,
                     const float* __restrict__ Whh, const float* __restrict__ bih,
                     const float* __restrict__ bhh, float* __restrict__ out,
                     uint32_t* hx /* [2][BB][128] agent exchange */) {
    const int b   = blockIdx.x >> 3;    // batch
    const int k   = blockIdx.x & 7;     // slice: owns h units [32k, 32k+32)
    const int tid = threadIdx.x;
    const int cg  = tid & 7;            // col-group: h cols [32cg,+32), x cols [16cg,+16)
    const int rb  = tid >> 3;           // row-group 0..63: local gate rows {2rb, 2rb+1}

    __shared__ uint32_t h_pk[8][20];    // packed h_t: [cg][16 u32] + 4 pad (banks disjoint)
    __shared__ uint32_t x_pk[2][8][12]; // packed x_t dbuf: [cg][8 u32] + 4 pad
    __shared__ float    G[128];         // our 128 gate pre-activations (no bias)
    __shared__ int      path_l[TT];

    // ---- weight slice -> named uint4 registers (48 u32/thread; fits 128-VGPR budget) ----
    const int r0 = rb << 1, r1 = r0 | 1;                    // local rows
    const int grow0 = ((r0 >> 5) << 8) + (k << 5) + (r0 & 31);
    const int grow1 = ((r1 >> 5) << 8) + (k << 5) + (r1 & 31);
    const float* wp0 = Whh + grow0 * HH + (cg << 5);
    const float* wp1 = Whh + grow1 * HH + (cg << 5);
    const uint4 wh0a = pk4(wp0),      wh0b = pk4(wp0 + 8),
                wh0c = pk4(wp0 + 16), wh0d = pk4(wp0 + 24);
    const uint4 wh1a = pk4(wp1),      wh1b = pk4(wp1 + 8),
                wh1c = pk4(wp1 + 16), wh1d = pk4(wp1 + 24);
    const float* xp0 = Wih + grow0 * DD + (cg << 4);
    const float* xp1 = Wih + grow1 * DD + (cg << 4);
    const uint4 wx0a = pk4(xp0), wx0b = pk4(xp0 + 8);
    const uint4 wx1a = pk4(xp1), wx1b = pk4(xp1 + 8);
    const int L = vlen[b];

    // biases for pointwise threads (unit u = tid < 32 -> global unit 32k+tid)
    float bi = 0.f, bf = 0.f, bg = 0.f, bo = 0.f;
    if (tid < 32) {
        const int u = (k << 5) + tid;
        bi = bih[u]       + bhh[u];
        bf = bih[256 + u] + bhh[256 + u];
        bg = bih[512 + u] + bhh[512 + u];
        bo = bih[768 + u] + bhh[768 + u];
    }
    path_l[tid] = path[b * TT + tid];               // 512 threads == TT
    if (tid < 160) ((uint32_t*)h_pk)[tid] = 0u;     // h_0 = 0 (pads included)
    __syncthreads();

    // x pipeline (waves 6-7): stage x_0, prefetch x_1
    float xr_next = 0.f;
    if (tid >= 384) {
        int e = tid - 384;
        float x0  = emb[(size_t)path_l[0] * DD + e];
        float x0h = __shfl_xor(x0, 1);
        if (!(e & 1)) x_pk[0][e >> 4][(e >> 1) & 7] = pk_f16(x0, x0h);
        xr_next = emb[(size_t)path_l[L > 1 ? 1 : 0] * DD + e];
    }
    float c_state = 0.f;
    __syncthreads();

    for (int t = 0; t < L; ++t) {
        const int slot  = t & 1;
        const int phase = (t >> 1) & 1;
        const uint32_t want = phase ? 0x40004000u : 0u;

        // ---- dots: 2 rows x (32 h + 16 x cols) = 48 dot2; LDS = 6 x ds_read_b128 ----
        const uint4 hv0 = *(const uint4*)&h_pk[cg][0];
        const uint4 hv1 = *(const uint4*)&h_pk[cg][4];
        const uint4 hv2 = *(const uint4*)&h_pk[cg][8];
        const uint4 hv3 = *(const uint4*)&h_pk[cg][12];
        const uint4 xv0 = *(const uint4*)&x_pk[slot][cg][0];
        const uint4 xv1 = *(const uint4*)&x_pk[slot][cg][4];
        float a0 = 0.f, a1 = 0.f;
        a0 = dot8(wh0a, hv0, a0); a0 = dot8(wh0b, hv1, a0);
        a0 = dot8(wh0c, hv2, a0); a0 = dot8(wh0d, hv3, a0);
        a0 = dot8(wx0a, xv0, a0); a0 = dot8(wx0b, xv1, a0);
        a1 = dot8(wh1a, hv0, a1); a1 = dot8(wh1b, hv1, a1);
        a1 = dot8(wh1c, hv2, a1); a1 = dot8(wh1d, hv3, a1);
        a1 = dot8(wx1a, xv0, a1); a1 = dot8(wx1b, xv1, a1);
        // 8-lane reduce (valid at all lanes after mirror; consumed at cg==0)
        a0 = dpp_add<0xB1>(a0); a0 = dpp_add<0x4E>(a0); a0 = dpp_add<0x141>(a0);
        a1 = dpp_add<0xB1>(a1); a1 = dpp_add<0x4E>(a1); a1 = dpp_add<0x141>(a1);
        if (cg == 0) *(float2*)&G[r0] = make_float2(a0, a1);
        __syncthreads();

        // ---- roles: tid<32 pointwise+publish | tid 64..176 poll | tid>=384 x-stage ----
        if (tid < 32) {
            float gi = fsig(G[tid] + bi);
            float gf = fsig(G[32 + tid] + bf);
            float gg = ftanh(G[64 + tid] + bg);
            float go = fsig(G[96 + tid] + bo);
            c_state  = gf * c_state + gi * gg;
            float h  = go * ftanh(c_state);
            if (t == L - 1) out[b * HH + (k << 5) + tid] = h;
            float h1 = __shfl_xor(h, 1);
            if (!(tid & 1)) {
                uint32_t pk = pk_f16(h, h1);
                int j = (k << 4) + (tid >> 1);               // global u32 idx (own block)
                h_pk[j >> 4][j & 15] = pk;                   // own slice via LDS
                __hip_atomic_store(&hx[(slot * BB + b) * 128 + j],
                                   phase ? ~pk : pk,
                                   __ATOMIC_RELAXED, __HIP_MEMORY_SCOPE_AGENT);
            }
        } else if (tid >= 64 && tid < 176) {
            if (t < L - 1) {
                int jj = tid - 64;                           // 112 remote u32s
                int j  = jj + (jj >= (k << 4) ? 16 : 0);     // skip own 16-u32 block
                uint32_t* addr = &hx[(slot * BB + b) * 128 + j];
                uint32_t v; int spins = 0;
                do {
                    v = __hip_atomic_load(addr, __ATOMIC_RELAXED, __HIP_MEMORY_SCOPE_AGENT);
                } while ((v & 0x40004000u) != want && ++spins < (1 << 20));
                h_pk[j >> 4][j & 15] = phase ? ~v : v;
            }
        } else if (tid >= 384) {
            int e = tid - 384;
            float xh = __shfl_xor(xr_next, 1);
            if (!(e & 1)) x_pk[slot ^ 1][e >> 4][(e >> 1) & 7] = pk_f16(xr_next, xh);
            int tpf = (t + 2 < TT) ? t + 2 : TT - 1;
            xr_next = emb[(size_t)path_l[tpf] * DD + e];     // prefetch x_{t+2}
        }
        __syncthreads();   // h_pk / x_pk ready for next step
    }
}

extern "C" void kernel_launch(void* const* d_in, const int* in_sizes, int n_in,
                              void* d_out, int out_size, void* d_ws, size_t ws_size,
                              hipStream_t stream) {
    const int*   path = (const int*)d_in[0];
    const int*   vlen = (const int*)d_in[1];
    const float* emb  = (const float*)d_in[2];
    const float* Wih  = (const float*)d_in[3];
    const float* Whh  = (const float*)d_in[4];
    const float* bih  = (const float*)d_in[5];
    const float* bhh  = (const float*)d_in[6];

    // exchange buffer 0xFF: bit14 set in both halves -> rejected by the phase-0
    // predicate at steps 0/1 (the only steps that can observe init data).
    (void)hipMemsetAsync(d_ws, 0xFF, (size_t)2 * BB * 128 * sizeof(uint32_t), stream);
    lstm_oct_kernel<<<512, 512, 0, stream>>>(path, vlen, emb, Wih, Whh, bih, bhh,
                                             (float*)d_out, (uint32_t*)d_ws);
}

// Round 11
// 820.787 us; speedup vs baseline: 1.3440x; 1.0848x over previous
//
#include <hip/hip_runtime.h>
#include <stdint.h>

// TrajEncoder: embedding gather + LSTM(D=128,H=256) over T=512, output h at valid_len-1.
// R11: 8 WGs x 256 THREADS per batch (grid 512, static blockIdx = b*8+k, 2 WGs/CU).
// Empirical allocator law (R6-R10): VGPR cap = 65536/block_size, honored fully only
// with an explicit launch_bounds minBlocks arg. 256 thr -> 256-VGPR cap; per-thread
// weights = 4 rows x (32h+16x cols) = 96 u32 as 24 named uint4s (+~55 working = ~150).
// R10's VGPR=60 + FETCH 64MB proved weights were re-loaded from L2 every step.
// h-exchange (R10-proven): agent-scope atomics, epoch-encoded values (phase0: bit14
// clear; phase1: ~pk), double-buffered slots, 0xFF init rejects phase-0.
// 8-lane DPP reduce: quad xor1, quad xor2, row_half_mirror (R6-proven).

#define BB 64
#define TT 512
#define DD 128
#define HH 256

typedef __fp16 half2v __attribute__((ext_vector_type(2)));

static __device__ __forceinline__ uint32_t pk_f16(float lo, float hi) {
    half2v h = __builtin_amdgcn_cvt_pkrtz(lo, hi);
    return __builtin_bit_cast(uint32_t, h);
}
static __device__ __forceinline__ uint4 pk4(const float* p) {
    return make_uint4(pk_f16(p[0], p[1]), pk_f16(p[2], p[3]),
                      pk_f16(p[4], p[5]), pk_f16(p[6], p[7]));
}
static __device__ __forceinline__ float dot2(uint32_t a, uint32_t b, float acc) {
    return __builtin_amdgcn_fdot2(__builtin_bit_cast(half2v, a),
                                  __builtin_bit_cast(half2v, b), acc, false);
}
static __device__ __forceinline__ float dot8(uint4 w, uint4 v, float a) {
    a = dot2(w.x, v.x, a); a = dot2(w.y, v.y, a);
    a = dot2(w.z, v.z, a); a = dot2(w.w, v.w, a);
    return a;
}

// a += a[perm(lane)] via DPP. 0xB1=quad xor1, 0x4E=quad xor2, 0x141=row_half_mirror
// (p <-> 7-p within each 8-lane half-row; symmetric => rotate-direction-proof).
template<int CTRL>
static __device__ __forceinline__ float dpp_add(float a) {
    int m = __builtin_amdgcn_update_dpp(0, __builtin_bit_cast(int, a), CTRL, 0xF, 0xF, false);
    return a + __builtin_bit_cast(float, m);
}

static __device__ __forceinline__ float fsig(float x)  { return 1.f / (1.f + __expf(-x)); }
static __device__ __forceinline__ float ftanh(float x) { return 1.f - 2.f / (__expf(2.f * x) + 1.f); }

__global__ __launch_bounds__(256, 2)
void lstm_oct256_kernel(const int* __restrict__ path, const int* __restrict__ vlen,
                        const float* __restrict__ emb, const float* __restrict__ Wih,
                        const float* __restrict__ Whh, const float* __restrict__ bih,
                        const float* __restrict__ bhh, float* __restrict__ out,
                        uint32_t* hx /* [2][BB][128] agent exchange */) {
    const int b   = blockIdx.x >> 3;    // batch
    const int k   = blockIdx.x & 7;     // slice: owns h units [32k, 32k+32)
    const int tid = threadIdx.x;
    const int cg  = tid & 7;            // col-group: h cols [32cg,+32), x cols [16cg,+16)
    const int rg  = tid >> 3;           // row-group 0..31: local gate rows 4rg..4rg+4

    __shared__ uint32_t h_pk[8][20];    // packed h_t: [cg][16 u32] + 4 pad
    __shared__ uint32_t x_pk[2][8][12]; // packed x_t dbuf: [cg][8 u32] + 4 pad
    __shared__ float    G[128];         // our 128 gate pre-activations (no bias)
    __shared__ int      path_l[TT];

    // ---- weight slice -> 24 named uint4 registers (96 u32/thread; cap = 256) ----
    // local rows 4rg+rr; global row = gate*256 + k*32 + unit
    const int l0 = rg << 2;
    const int gw0 = ((l0 >> 5) << 8) + (k << 5) + (l0 & 31);
    const int gw1 = (((l0 + 1) >> 5) << 8) + (k << 5) + ((l0 + 1) & 31);
    const int gw2 = (((l0 + 2) >> 5) << 8) + (k << 5) + ((l0 + 2) & 31);
    const int gw3 = (((l0 + 3) >> 5) << 8) + (k << 5) + ((l0 + 3) & 31);
    const float* h0p = Whh + gw0 * HH + (cg << 5);
    const float* h1p = Whh + gw1 * HH + (cg << 5);
    const float* h2p = Whh + gw2 * HH + (cg << 5);
    const float* h3p = Whh + gw3 * HH + (cg << 5);
    const uint4 w0a = pk4(h0p), w0b = pk4(h0p + 8), w0c = pk4(h0p + 16), w0d = pk4(h0p + 24);
    const uint4 w1a = pk4(h1p), w1b = pk4(h1p + 8), w1c = pk4(h1p + 16), w1d = pk4(h1p + 24);
    const uint4 w2a = pk4(h2p), w2b = pk4(h2p + 8), w2c = pk4(h2p + 16), w2d = pk4(h2p + 24);
    const uint4 w3a = pk4(h3p), w3b = pk4(h3p + 8), w3c = pk4(h3p + 16), w3d = pk4(h3p + 24);
    const float* x0p = Wih + gw0 * DD + (cg << 4);
    const float* x1p = Wih + gw1 * DD + (cg << 4);
    const float* x2p = Wih + gw2 * DD + (cg << 4);
    const float* x3p = Wih + gw3 * DD + (cg << 4);
    const uint4 v0a = pk4(x0p), v0b = pk4(x0p + 8);
    const uint4 v1a = pk4(x1p), v1b = pk4(x1p + 8);
    const uint4 v2a = pk4(x2p), v2b = pk4(x2p + 8);
    const uint4 v3a = pk4(x3p), v3b = pk4(x3p + 8);
    const int L = vlen[b];

    // biases for pointwise threads (unit = 32k + tid, tid < 32)
    float bi = 0.f, bf = 0.f, bg = 0.f, bo = 0.f;
    if (tid < 32) {
        const int u = (k << 5) + tid;
        bi = bih[u]       + bhh[u];
        bf = bih[256 + u] + bhh[256 + u];
        bg = bih[512 + u] + bhh[512 + u];
        bo = bih[768 + u] + bhh[768 + u];
    }
    path_l[tid]       = path[b * TT + tid];
    path_l[tid + 256] = path[b * TT + tid + 256];
    if (tid < 160) ((uint32_t*)h_pk)[tid] = 0u;     // h_0 = 0 (pads included)
    __syncthreads();

    // x pipeline (wave 3, threads 192..256): stage x_0, prefetch x_1 (float2/thread)
    float2 xr_next = make_float2(0.f, 0.f);
    if (tid >= 192) {
        int e = tid - 192;                           // u32 index 0..63
        float2 x0 = *(const float2*)&emb[(size_t)path_l[0] * DD + (e << 1)];
        x_pk[0][e >> 3][e & 7] = pk_f16(x0.x, x0.y);
        xr_next = *(const float2*)&emb[(size_t)path_l[L > 1 ? 1 : 0] * DD + (e << 1)];
    }
    float c_state = 0.f;
    __syncthreads();

    for (int t = 0; t < L; ++t) {
        const int slot  = t & 1;
        const int phase = (t >> 1) & 1;
        const uint32_t want = phase ? 0x40004000u : 0u;

        // ---- dots: 4 rows x (32 h + 16 x cols) = 96 dot2; LDS = 6 x ds_read_b128 ----
        const uint4 hv0 = *(const uint4*)&h_pk[cg][0];
        const uint4 hv1 = *(const uint4*)&h_pk[cg][4];
        const uint4 hv2 = *(const uint4*)&h_pk[cg][8];
        const uint4 hv3 = *(const uint4*)&h_pk[cg][12];
        const uint4 xv0 = *(const uint4*)&x_pk[slot][cg][0];
        const uint4 xv1 = *(const uint4*)&x_pk[slot][cg][4];
        float a0 = 0.f, a1 = 0.f, a2 = 0.f, a3 = 0.f;
        a0 = dot8(w0a, hv0, a0); a0 = dot8(w0b, hv1, a0);
        a0 = dot8(w0c, hv2, a0); a0 = dot8(w0d, hv3, a0);
        a0 = dot8(v0a, xv0, a0); a0 = dot8(v0b, xv1, a0);
        a1 = dot8(w1a, hv0, a1); a1 = dot8(w1b, hv1, a1);
        a1 = dot8(w1c, hv2, a1); a1 = dot8(w1d, hv3, a1);
        a1 = dot8(v1a, xv0, a1); a1 = dot8(v1b, xv1, a1);
        a2 = dot8(w2a, hv0, a2); a2 = dot8(w2b, hv1, a2);
        a2 = dot8(w2c, hv2, a2); a2 = dot8(w2d, hv3, a2);
        a2 = dot8(v2a, xv0, a2); a2 = dot8(v2b, xv1, a2);
        a3 = dot8(w3a, hv0, a3); a3 = dot8(w3b, hv1, a3);
        a3 = dot8(w3c, hv2, a3); a3 = dot8(w3d, hv3, a3);
        a3 = dot8(v3a, xv0, a3); a3 = dot8(v3b, xv1, a3);
        a0 = dpp_add<0xB1>(a0); a0 = dpp_add<0x4E>(a0); a0 = dpp_add<0x141>(a0);
        a1 = dpp_add<0xB1>(a1); a1 = dpp_add<0x4E>(a1); a1 = dpp_add<0x141>(a1);
        a2 = dpp_add<0xB1>(a2); a2 = dpp_add<0x4E>(a2); a2 = dpp_add<0x141>(a2);
        a3 = dpp_add<0xB1>(a3); a3 = dpp_add<0x4E>(a3); a3 = dpp_add<0x141>(a3);
        if (cg == 0) *(float4*)&G[l0] = make_float4(a0, a1, a2, a3);
        __syncthreads();

        // ---- roles: wave0 pointwise+publish | waves1-2 poll | wave3 x-stage ----
        if (tid < 32) {
            float gi = fsig(G[tid] + bi);
            float gf = fsig(G[32 + tid] + bf);
            float gg = ftanh(G[64 + tid] + bg);
            float go = fsig(G[96 + tid] + bo);
            c_state  = gf * c_state + gi * gg;
            float h  = go * ftanh(c_state);
            if (t == L - 1) out[b * HH + (k << 5) + tid] = h;
            float h1 = __shfl_xor(h, 1);
            if (!(tid & 1)) {
                uint32_t pk = pk_f16(h, h1);
                int j = (k << 4) + (tid >> 1);               // global u32 idx (own block)
                h_pk[j >> 4][j & 15] = pk;                   // own slice via LDS
                __hip_atomic_store(&hx[(slot * BB + b) * 128 + j],
                                   phase ? ~pk : pk,
                                   __ATOMIC_RELAXED, __HIP_MEMORY_SCOPE_AGENT);
            }
        } else if (tid >= 64 && tid < 176) {
            if (t < L - 1) {
                int jj = tid - 64;                           // 112 remote u32s
                int j  = jj + (jj >= (k << 4) ? 16 : 0);     // skip own 16-u32 block
                uint32_t* addr = &hx[(slot * BB + b) * 128 + j];
                uint32_t v; int spins = 0;
                do {
                    v = __hip_atomic_load(addr, __ATOMIC_RELAXED, __HIP_MEMORY_SCOPE_AGENT);
                } while ((v & 0x40004000u) != want && ++spins < (1 << 20));
                h_pk[j >> 4][j & 15] = phase ? ~v : v;
            }
        } else if (tid >= 192) {
            int e = tid - 192;                               // u32 index 0..63
            x_pk[slot ^ 1][e >> 3][e & 7] = pk_f16(xr_next.x, xr_next.y);
            int tpf = (t + 2 < TT) ? t + 2 : TT - 1;
            xr_next = *(const float2*)&emb[(size_t)path_l[tpf] * DD + (e << 1)];
        }
        __syncthreads();   // h_pk / x_pk ready for next step
    }
}

extern "C" void kernel_launch(void* const* d_in, const int* in_sizes, int n_in,
                              void* d_out, int out_size, void* d_ws, size_t ws_size,
                              hipStream_t stream) {
    const int*   path = (const int*)d_in[0];
    const int*   vlen = (const int*)d_in[1];
    const float* emb  = (const float*)d_in[2];
    const float* Wih  = (const float*)d_in[3];
    const float* Whh  = (const float*)d_in[4];
    const float* bih  = (const float*)d_in[5];
    const float* bhh  = (const float*)d_in[6];

    // exchange buffer 0xFF: bit14 set in both halves -> rejected by the phase-0
    // predicate at steps 0/1 (the only steps that can observe init data).
    (void)hipMemsetAsync(d_ws, 0xFF, (size_t)2 * BB * 128 * sizeof(uint32_t), stream);
    lstm_oct256_kernel<<<512, 256, 0, stream>>>(path, vlen, emb, Wih, Whh, bih, bhh,
                                                (float*)d_out, (uint32_t*)d_ws);
}